// Round 19
// baseline (17.085 us; speedup 1.0000x reference)
//
#include <hip/hip_runtime.h>
#include <math.h>

#define NUM_HEADS 16
#define DIM_HID 64
#define NUM_GAUSS 251
#define W_SCA_COLS 320   // DIM_HID + 256
#define GP 20            // padded stride (floats): 80B, 16B-aligned
#define RAD 0.14f        // window radius
#define NW 8             // fixed window iterations
#define TPB 832          // 13 waves; 241 blocks -> 1 generation/CU
#define EPB 832
#define NWAVES 13
#define STG 768          // staging threads (waves 0-11); wave 12 does the fold
#define NSLICE 32
#define SLF4 1172        // float4 per pos slice

typedef float f4 __attribute__((ext_vector_type(4)));
struct F3 { float x, y, z; };

// ---------------------------------------------------------------------------
// r19 = r18 geometry + CRITICAL-PATH COMPRESSION of the block prologue.
// r18's serial path: staging(1RT) -> barrier -> wave0 weff fold(1RT) ->
// A/B fold(1RT) -> barrier -> gather(1RT) -> body  (~3RT + 2 barriers).
// Changes (one mechanism: overlap):
//   - fold runs on WAVE 12 (tid>=768) CONCURRENTLY with waves 0-11 staging
//     (fold is wave-internal: wave_barrier ordering, no __syncthreads)
//   - pos gather issued BEFORE staging (only depends on idx; flight hides
//     under staging + barrier)
//   - ONE __syncthreads total (was 2)
// Frozen: NT stores, cacheable loads, per-XCD warming sweep, LDS transpose
// stores, fixed-8 window, s_load gate, 1 block/CU geometry.
//
// Algebraic collapse validated r2-r18 (absmax pinned 3.9e-3 vs 1.57e-2):
//   weff = w_vec1 @ w_edge;  A = |weff| @ w_sca[:,:64]^T;  B = w_vec2 @ weff
//   out_sca = un*A + etype_row + gauss_window(d)
//   output_vec = (sigmoid(out_sca@Wg^T + b) * B)^2 * un^2
// ---------------------------------------------------------------------------
__global__ __launch_bounds__(TPB) void edge_kernel(
    const int* __restrict__ idxA,     // [E]
    const int* __restrict__ idxB,     // [E]
    const float* __restrict__ feat,   // [E,5]
    const float* __restrict__ pos,    // [N,3]
    const float* __restrict__ w_edge, // [64]
    const float* __restrict__ w_vec1, // [64,64]
    const float* __restrict__ w_vec2, // [16,64]
    const float* __restrict__ w_sca,  // [16,320]
    const float* __restrict__ w_gate, // [16,16]
    const float* __restrict__ b_gate, // [16]
    float* __restrict__ out,
    int E, int nposf)
{
    __shared__ __align__(16) float wg[NUM_GAUSS * GP];
    __shared__ __align__(16) float wt5[5 * GP];
    __shared__ __align__(16) float weff[64];
    __shared__ __align__(16) float As[16], Bs[16];
    __shared__ __align__(16) float sOut[NWAVES][64 * GP];

    const int tid = threadIdx.x;
    const int e  = blockIdx.x * EPB + tid;
    const int ec = (e < E) ? e : (E - 1);

    // --- (1) per-edge loads: idx + feat (cacheable) ---
    const int na = idxA[ec];
    const int nb = idxB[ec];
    float f14[4];
    __builtin_memcpy(f14, feat + ec * 5 + 1, 16);

    // --- (2) pos warming sweep (sequential f4, per-XCD slice) ---
    {
        const f4* pos4 = (const f4*)pos;
        const int nf4 = nposf >> 2;
        const int s = (int)((blockIdx.x >> 3) % NSLICE);
        #pragma unroll
        for (int r = 0; r < 2; ++r) {
            const int k = r * TPB + tid;
            const int j = s * SLF4 + k;
            if (k < SLF4 && j < nf4) {
                const f4 v = pos4[j];
                asm volatile("" :: "v"(v.x), "v"(v.y), "v"(v.z), "v"(v.w));
            }
        }
    }

    // --- (3) pos gather issued NOW: flight hides under staging + barrier ---
    F3 pa3, pb3;
    __builtin_memcpy(&pa3, pos + na * 3, 12);
    __builtin_memcpy(&pb3, pos + nb * 3, 12);

    // --- (4a) waves 0-11: stage wg + wt5 ---
    if (tid < STG) {
        for (int j = tid; j < 16 * NUM_GAUSS; j += STG) {
            int o = j / NUM_GAUSS;
            int g = j - o * NUM_GAUSS;
            wg[g * GP + o] = w_sca[o * W_SCA_COLS + DIM_HID + g];
        }
        if (tid >= STG - 80) {                 // 80 threads of wave 10/11
            int k = tid - (STG - 80);
            int t = k >> 4, o = k & 15;
            wt5[t * GP + o] = w_sca[o * W_SCA_COLS + DIM_HID + NUM_GAUSS + t];
        }
    }
    // --- (4b) wave 12: fold (wave-internal, concurrent with staging) ---
    else {
        const int h = tid - STG;               // 0..63
        const float4* wrow = (const float4*)(w_vec1 + h * 64);
        float s = 0.f;
        #pragma unroll
        for (int c4 = 0; c4 < 16; ++c4) {
            float4 v = wrow[c4];
            s += v.x * w_edge[c4*4+0] + v.y * w_edge[c4*4+1]
               + v.z * w_edge[c4*4+2] + v.w * w_edge[c4*4+3];
        }
        weff[h] = s;
    }
    __builtin_amdgcn_wave_barrier();           // pin DS order within wave 12
    if (tid >= STG && tid < STG + 16) {
        const int o = tid - STG;
        const float4* srow = (const float4*)(w_sca + o * W_SCA_COLS);
        const float4* vrow = (const float4*)(w_vec2 + o * 64);
        float a2 = 0.f, b2 = 0.f;
        #pragma unroll
        for (int k4 = 0; k4 < 16; ++k4) {
            float4 sv = srow[k4];
            float4 vv = vrow[k4];
            float4 wv = *(const float4*)&weff[k4 * 4];
            a2 += fabsf(wv.x)*sv.x + fabsf(wv.y)*sv.y + fabsf(wv.z)*sv.z + fabsf(wv.w)*sv.w;
            b2 += wv.x*vv.x + wv.y*vv.y + wv.z*vv.z + wv.w*vv.w;
        }
        As[o] = a2;
        Bs[o] = b2;
    }
    __syncthreads();                           // the ONLY block barrier

    // --- geometry (pos long since arrived) ---
    const float vx = pa3.x - pb3.x, vy = pa3.y - pb3.y, vz = pa3.z - pb3.z;
    const float d  = sqrtf(vx*vx + vy*vy + vz*vz);
    const float un = d * __builtin_amdgcn_rcpf(d + 1e-7f);
    const float u2 = un * un;
    const int ti = (int)(f14[0] + 2.f*f14[1] + 3.f*f14[2] + 4.f*f14[3] + 0.5f);

    int glo = (int)ceilf((d - RAD) * 25.f);
    glo = glo < 0 ? 0 : (glo > NUM_GAUSS - NW ? NUM_GAUSS - NW : glo);
    const float x0 = d - (float)glo * 0.04f;

    // --- acc init: un*A + etype row ---
    float acc[16];
    {
        const float4* ar  = (const float4*)As;
        const float4* t0r = (const float4*)&wt5[ti * GP];
        #pragma unroll
        for (int qq = 0; qq < 4; ++qq) {
            const float4 av = ar[qq];
            const float4 tv = t0r[qq];
            acc[4*qq+0] = fmaf(un, av.x, tv.x);
            acc[4*qq+1] = fmaf(un, av.y, tv.y);
            acc[4*qq+2] = fmaf(un, av.z, tv.z);
            acc[4*qq+3] = fmaf(un, av.w, tv.w);
        }
    }

    // --- fixed-8 gauss window ---
    {
        const float C2 = -312.5f * 1.44269504088896340736f;
        const float* base = &wg[glo * GP];
        #pragma unroll
        for (int i = 0; i < NW; ++i) {
            const float t = x0 - (float)i * 0.04f;
            const float w = exp2f(C2 * t * t);
            const float4* row = (const float4*)(base + i * GP);
            #pragma unroll
            for (int qq = 0; qq < 4; ++qq) {
                const float4 v = row[qq];
                acc[4*qq+0] = fmaf(w, v.x, acc[4*qq+0]);
                acc[4*qq+1] = fmaf(w, v.y, acc[4*qq+1]);
                acc[4*qq+2] = fmaf(w, v.z, acc[4*qq+2]);
                acc[4*qq+3] = fmaf(w, v.w, acc[4*qq+3]);
            }
        }
    }

    // --- transpose-store out_sca: LDS tile -> contiguous NT stores ---
    const int wv = tid >> 6, l = tid & 63;
    float* sw = sOut[wv];
    const int wbase = blockIdx.x * EPB + wv * 64;
    #pragma unroll
    for (int qq = 0; qq < 4; ++qq)
        *(float4*)&sw[l * GP + 4*qq] =
            make_float4(acc[4*qq], acc[4*qq+1], acc[4*qq+2], acc[4*qq+3]);
    __builtin_amdgcn_wave_barrier();
    #pragma unroll
    for (int s = 0; s < 4; ++s) {
        const int r = s * 16 + (l >> 2);
        const int cc = (l & 3) * 4;
        const f4 v = *(const f4*)&sw[r * GP + cc];
        if (wbase + r < E)
            __builtin_nontemporal_store(v, (f4*)(out + (size_t)(wbase + r) * 16 + cc));
    }
    __builtin_amdgcn_wave_barrier();

    // --- gate: wave-uniform s_load weights ---
    const float NL2E = -1.44269504088896340736f;
    #pragma unroll
    for (int oq = 0; oq < 16; oq += 4) {
        float ov[4];
        #pragma unroll
        for (int oi = 0; oi < 4; ++oi) {
            const int o = oq + oi;
            float x = b_gate[o];
            #pragma unroll
            for (int p = 0; p < 16; ++p) x = fmaf(acc[p], w_gate[o * 16 + p], x);
            const float gate = __builtin_amdgcn_rcpf(1.0f + exp2f(NL2E * x));
            const float gv = gate * Bs[o];
            ov[oi] = gv * gv * u2;
        }
        *(float4*)&sw[l * GP + oq] = make_float4(ov[0], ov[1], ov[2], ov[3]);
    }
    __builtin_amdgcn_wave_barrier();
    float* outv = out + (size_t)E * 16;
    #pragma unroll
    for (int s = 0; s < 4; ++s) {
        const int r = s * 16 + (l >> 2);
        const int cc = (l & 3) * 4;
        const f4 v = *(const f4*)&sw[r * GP + cc];
        if (wbase + r < E)
            __builtin_nontemporal_store(v, (f4*)(outv + (size_t)(wbase + r) * 16 + cc));
    }
}

extern "C" void kernel_launch(void* const* d_in, const int* in_sizes, int n_in,
                              void* d_out, int out_size, void* d_ws, size_t ws_size,
                              hipStream_t stream) {
    const int*   idx    = (const int*)d_in[0];
    const float* feat   = (const float*)d_in[1];
    const float* pos    = (const float*)d_in[2];
    const float* w_edge = (const float*)d_in[3];
    const float* w_vec1 = (const float*)d_in[4];
    const float* w_vec2 = (const float*)d_in[5];
    const float* w_sca  = (const float*)d_in[6];
    const float* w_gate = (const float*)d_in[7];
    const float* b_gate = (const float*)d_in[8];
    float* out = (float*)d_out;

    const int E = in_sizes[0] / 2;
    const int nposf = in_sizes[2];
    const int nblk = (E + EPB - 1) / EPB;   // 241 blocks for E=200K
    edge_kernel<<<nblk, TPB, 0, stream>>>(idx, idx + E, feat, pos,
                                          w_edge, w_vec1, w_vec2,
                                          w_sca, w_gate, b_gate, out, E, nposf);
}

// Round 20
// 16.600 us; speedup vs baseline: 1.0292x; 1.0292x over previous
//
#include <hip/hip_runtime.h>
#include <math.h>

#define NUM_HEADS 16
#define DIM_HID 64
#define NUM_GAUSS 251
#define W_SCA_COLS 320   // DIM_HID + 256
#define GP 20            // padded stride (floats): 80B, 16B-aligned
#define RAD 0.14f        // window radius
#define NW 8             // fixed window iterations
#define TPB 832          // 13 waves; 241 blocks -> exactly 1 generation/CU
#define EPB 832
#define NWAVES 13
#define NSLICE 32        // per-XCD pos slices
#define SLF4 1172        // float4 per slice (ceil(37500/32))

typedef float f4 __attribute__((ext_vector_type(4)));
struct F3 { float x, y, z; };

// ---------------------------------------------------------------------------
// r20 = r18 VERBATIM (measured best: 16.64us). r19's prologue-overlap
// restructure regressed (+0.45) -> reverted; that closed the last open
// structural theory.
//
// Final cost model (measured): warm body 6.8us (r14; NT-write floor 4.1us),
// per-replay cold re-establishment ~8us (harness's 268MB poison fills sweep
// L2+L3 between replays -> every replay cold by construction), launch ~2us.
// Ladder: 36.2 -> 25.6 (LDS restructure) -> 24.0 (window) -> 22.0 (NT
// stores) -> 21.3 (cacheable loads) -> 20.2 (pos warm sweep) -> 17.4
// (gens 1.5) -> 16.6 (gens 1.0). Falsified: LDS count, occupancy, store
// scatter, prologue amortization/overlap, spills (fixed), L2 interference
// (partial). Remaining time is cold-memory physics, not kernel structure.
//
// Algebraic collapse validated r2-r19 (absmax pinned 3.9e-3 vs 1.57e-2):
//   weff = w_vec1 @ w_edge;  A = |weff| @ w_sca[:,:64]^T;  B = w_vec2 @ weff
//   out_sca = un*A + etype_row + gauss_window(d)
//   output_vec = (sigmoid(out_sca@Wg^T + b) * B)^2 * un^2
// ---------------------------------------------------------------------------
__global__ __launch_bounds__(TPB) void edge_kernel(
    const int* __restrict__ idxA,     // [E]
    const int* __restrict__ idxB,     // [E]
    const float* __restrict__ feat,   // [E,5]
    const float* __restrict__ pos,    // [N,3]
    const float* __restrict__ w_edge, // [64]
    const float* __restrict__ w_vec1, // [64,64]
    const float* __restrict__ w_vec2, // [16,64]
    const float* __restrict__ w_sca,  // [16,320]
    const float* __restrict__ w_gate, // [16,16]
    const float* __restrict__ b_gate, // [16]
    float* __restrict__ out,
    int E, int nposf)                 // nposf = floats in pos (N*3)
{
    __shared__ __align__(16) float wg[NUM_GAUSS * GP];
    __shared__ __align__(16) float wt5[5 * GP];
    __shared__ __align__(16) float weff[64];
    __shared__ __align__(16) float As[16], Bs[16];
    __shared__ __align__(16) float sOut[NWAVES][64 * GP];

    const int tid = threadIdx.x;
    const int e  = blockIdx.x * EPB + tid;
    const int ec = (e < E) ? e : (E - 1);

    // --- early per-edge loads (cacheable): idx + feat ---
    const int na = idxA[ec];
    const int nb = idxB[ec];
    float f14[4];
    __builtin_memcpy(f14, feat + ec * 5 + 1, 16);  // one dwordx4

    // --- pos L2-warming sweep: sequential f4 reads of this XCD's slice ---
    {
        const f4* pos4 = (const f4*)pos;
        const int nf4 = nposf >> 2;                       // 37500
        const int s = (int)((blockIdx.x >> 3) % NSLICE);  // per-XCD slice id
        #pragma unroll
        for (int r = 0; r < 2; ++r) {
            const int k = r * TPB + tid;
            const int j = s * SLF4 + k;
            if (k < SLF4 && j < nf4) {
                const f4 v = pos4[j];
                asm volatile("" :: "v"(v.x), "v"(v.y), "v"(v.z), "v"(v.w));
            }
        }
    }

    // --- block prologue (staging overlaps the warming sweep's flight) ---
    for (int j = tid; j < 16 * NUM_GAUSS; j += TPB) {
        int o = j / NUM_GAUSS;
        int g = j - o * NUM_GAUSS;
        wg[g * GP + o] = w_sca[o * W_SCA_COLS + DIM_HID + g];
    }
    if (tid < 80) {
        int t = tid >> 4, o = tid & 15;
        wt5[t * GP + o] = w_sca[o * W_SCA_COLS + DIM_HID + NUM_GAUSS + t];
    }
    if (tid < 64) {
        const float4* wrow = (const float4*)(w_vec1 + tid * 64);
        float s = 0.f;
        #pragma unroll
        for (int c4 = 0; c4 < 16; ++c4) {
            float4 v = wrow[c4];
            s += v.x * w_edge[c4*4+0] + v.y * w_edge[c4*4+1]
               + v.z * w_edge[c4*4+2] + v.w * w_edge[c4*4+3];
        }
        weff[tid] = s;
    }
    __syncthreads();
    if (tid < 16) {
        const float4* srow = (const float4*)(w_sca + tid * W_SCA_COLS);
        const float4* vrow = (const float4*)(w_vec2 + tid * 64);
        float a2 = 0.f, b2 = 0.f;
        #pragma unroll
        for (int k4 = 0; k4 < 16; ++k4) {
            float4 sv = srow[k4];
            float4 vv = vrow[k4];
            float4 wv = *(const float4*)&weff[k4 * 4];
            a2 += fabsf(wv.x)*sv.x + fabsf(wv.y)*sv.y + fabsf(wv.z)*sv.z + fabsf(wv.w)*sv.w;
            b2 += wv.x*vv.x + wv.y*vv.y + wv.z*vv.z + wv.w*vv.w;
        }
        As[tid] = a2;
        Bs[tid] = b2;
    }
    __syncthreads();

    // --- pos gather NOW (L2 warm / lines in flight) ---
    F3 pa3, pb3;
    __builtin_memcpy(&pa3, pos + na * 3, 12);
    __builtin_memcpy(&pb3, pos + nb * 3, 12);

    // --- geometry ---
    const float vx = pa3.x - pb3.x, vy = pa3.y - pb3.y, vz = pa3.z - pb3.z;
    const float d  = sqrtf(vx*vx + vy*vy + vz*vz);
    const float un = d * __builtin_amdgcn_rcpf(d + 1e-7f);
    const float u2 = un * un;
    const int ti = (int)(f14[0] + 2.f*f14[1] + 3.f*f14[2] + 4.f*f14[3] + 0.5f);

    int glo = (int)ceilf((d - RAD) * 25.f);
    glo = glo < 0 ? 0 : (glo > NUM_GAUSS - NW ? NUM_GAUSS - NW : glo);
    const float x0 = d - (float)glo * 0.04f;

    // --- acc init: un*A + etype row ---
    float acc[16];
    {
        const float4* ar  = (const float4*)As;
        const float4* t0r = (const float4*)&wt5[ti * GP];
        #pragma unroll
        for (int qq = 0; qq < 4; ++qq) {
            const float4 av = ar[qq];
            const float4 tv = t0r[qq];
            acc[4*qq+0] = fmaf(un, av.x, tv.x);
            acc[4*qq+1] = fmaf(un, av.y, tv.y);
            acc[4*qq+2] = fmaf(un, av.z, tv.z);
            acc[4*qq+3] = fmaf(un, av.w, tv.w);
        }
    }

    // --- fixed-8 gauss window ---
    {
        const float C2 = -312.5f * 1.44269504088896340736f;  // coeff * log2(e)
        const float* base = &wg[glo * GP];
        #pragma unroll
        for (int i = 0; i < NW; ++i) {
            const float t = x0 - (float)i * 0.04f;
            const float w = exp2f(C2 * t * t);
            const float4* row = (const float4*)(base + i * GP);
            #pragma unroll
            for (int qq = 0; qq < 4; ++qq) {
                const float4 v = row[qq];
                acc[4*qq+0] = fmaf(w, v.x, acc[4*qq+0]);
                acc[4*qq+1] = fmaf(w, v.y, acc[4*qq+1]);
                acc[4*qq+2] = fmaf(w, v.z, acc[4*qq+2]);
                acc[4*qq+3] = fmaf(w, v.w, acc[4*qq+3]);
            }
        }
    }

    // --- transpose-store out_sca: LDS tile -> contiguous NT stores ---
    const int wv = tid >> 6, l = tid & 63;
    float* sw = sOut[wv];
    const int wbase = blockIdx.x * EPB + wv * 64;
    #pragma unroll
    for (int qq = 0; qq < 4; ++qq)
        *(float4*)&sw[l * GP + 4*qq] =
            make_float4(acc[4*qq], acc[4*qq+1], acc[4*qq+2], acc[4*qq+3]);
    __builtin_amdgcn_wave_barrier();
    #pragma unroll
    for (int s = 0; s < 4; ++s) {
        const int r = s * 16 + (l >> 2);
        const int cc = (l & 3) * 4;
        const f4 v = *(const f4*)&sw[r * GP + cc];
        if (wbase + r < E)
            __builtin_nontemporal_store(v, (f4*)(out + (size_t)(wbase + r) * 16 + cc));
    }
    __builtin_amdgcn_wave_barrier();

    // --- gate: wave-uniform s_load weights ---
    const float NL2E = -1.44269504088896340736f;
    #pragma unroll
    for (int oq = 0; oq < 16; oq += 4) {
        float ov[4];
        #pragma unroll
        for (int oi = 0; oi < 4; ++oi) {
            const int o = oq + oi;
            float x = b_gate[o];
            #pragma unroll
            for (int p = 0; p < 16; ++p) x = fmaf(acc[p], w_gate[o * 16 + p], x);
            const float gate = __builtin_amdgcn_rcpf(1.0f + exp2f(NL2E * x));
            const float gv = gate * Bs[o];
            ov[oi] = gv * gv * u2;
        }
        *(float4*)&sw[l * GP + oq] = make_float4(ov[0], ov[1], ov[2], ov[3]);
    }
    __builtin_amdgcn_wave_barrier();
    float* outv = out + (size_t)E * 16;
    #pragma unroll
    for (int s = 0; s < 4; ++s) {
        const int r = s * 16 + (l >> 2);
        const int cc = (l & 3) * 4;
        const f4 v = *(const f4*)&sw[r * GP + cc];
        if (wbase + r < E)
            __builtin_nontemporal_store(v, (f4*)(outv + (size_t)(wbase + r) * 16 + cc));
    }
}

extern "C" void kernel_launch(void* const* d_in, const int* in_sizes, int n_in,
                              void* d_out, int out_size, void* d_ws, size_t ws_size,
                              hipStream_t stream) {
    const int*   idx    = (const int*)d_in[0];
    const float* feat   = (const float*)d_in[1];
    const float* pos    = (const float*)d_in[2];
    const float* w_edge = (const float*)d_in[3];
    const float* w_vec1 = (const float*)d_in[4];
    const float* w_vec2 = (const float*)d_in[5];
    const float* w_sca  = (const float*)d_in[6];
    const float* w_gate = (const float*)d_in[7];
    const float* b_gate = (const float*)d_in[8];
    float* out = (float*)d_out;

    const int E = in_sizes[0] / 2;
    const int nposf = in_sizes[2];    // N*3 floats
    const int nblk = (E + EPB - 1) / EPB;   // 241 blocks for E=200K
    edge_kernel<<<nblk, TPB, 0, stream>>>(idx, idx + E, feat, pos,
                                          w_edge, w_vec1, w_vec2,
                                          w_sca, w_gate, b_gate, out, E, nposf);
}